// Round 5
// baseline (2122.891 us; speedup 1.0000x reference)
//
#include <hip/hip_runtime.h>

#define T_SEQ 2048
#define BT    8192
#define DM    512
#define NR    8
#define NSTEP 5
#define K1    1536   // 3*D
#define H2    1024   // 2*D
#define VSZ   32000
#define HN    8192   // NR*H2

using ushort_t = unsigned short;
using bf16x8 = __attribute__((ext_vector_type(8))) __bf16;
using f32x16 = __attribute__((ext_vector_type(16))) float;

__device__ __forceinline__ ushort_t f2bf(float f) {
    union { float f; unsigned u; } v; v.f = f;
    unsigned r = v.u + 0x7FFFu + ((v.u >> 16) & 1u);
    return (ushort_t)(r >> 16);
}

__device__ __forceinline__ float bf2f(unsigned hi) {
    union { unsigned u; float f; } v; v.u = hi << 16;
    return v.f;
}

__device__ __forceinline__ void gload16(const void* g, void* l) {
    __builtin_amdgcn_global_load_lds((const __attribute__((address_space(1))) void*)g,
                                     (__attribute__((address_space(3))) void*)l, 16, 0, 0);
}

// gelu(tanh form) = x * sigmoid(x*(2.3022861 + 0.10294456*x^2))  [exact identity]
__device__ __forceinline__ float gelu_fast(float x) {
    float x2 = x * x;
    float u  = x * fmaf(x2, 0.10294456f, 2.3022861f);   // 2y*log2(e)
    float e  = exp2f(-u);
    return x * __builtin_amdgcn_rcpf(1.0f + e);
}

#define BAR()     __builtin_amdgcn_s_barrier()
#define VMCNT4()  asm volatile("s_waitcnt vmcnt(4)" ::: "memory")
#define VMCNT0()  asm volatile("s_waitcnt vmcnt(0)" ::: "memory")
#define LGKM0()   asm volatile("s_waitcnt lgkmcnt(0)" ::: "memory")

// transpose f32 src[z][K][N] -> bf16 dst[z*dstBatch + n*dstRow + k]
__global__ void transpose_f32_bf16(const float* __restrict__ src, ushort_t* __restrict__ dst,
                                   int K, int N, long long srcBatch, long long dstBatch, int dstRow)
{
    __shared__ float tile[32][33];
    src += (size_t)blockIdx.z * srcBatch;
    dst += (size_t)blockIdx.z * dstBatch;
    int n0 = blockIdx.x * 32, k0 = blockIdx.y * 32;
    int tx = threadIdx.x, ty = threadIdx.y;
    #pragma unroll
    for (int i = 0; i < 32; i += 8)
        tile[ty + i][tx] = src[(size_t)(k0 + ty + i) * N + (n0 + tx)];
    __syncthreads();
    #pragma unroll
    for (int i = 0; i < 32; i += 8)
        dst[(size_t)(n0 + ty + i) * dstRow + (k0 + tx)] = f2bf(tile[tx][ty + i]);
}

__global__ void embed_pos(const int* __restrict__ tokens, const float* __restrict__ emb,
                          const float* __restrict__ pos, float* __restrict__ x,
                          ushort_t* __restrict__ xbf)
{
    int row = blockIdx.x;
    int t = row & (T_SEQ - 1);
    int tok = tokens[row];
    int i = threadIdx.x;              // 256 threads * float2 = 512 floats
    float2 e = ((const float2*)(emb + (size_t)tok * DM))[i];
    float2 p = ((const float2*)(pos + (size_t)t * DM))[i];
    float2 v = make_float2(e.x + p.x, e.y + p.y);
    ((float2*)(x + (size_t)row * DM))[i] = v;
    ushort_t bb[2] = { f2bf(v.x), f2bf(v.y) };
    ((unsigned*)(xbf + (size_t)row * DM))[i] = *(const unsigned*)bb;
}

__global__ void rw_kernel(const float* __restrict__ gate, const float* __restrict__ selw,
                          const float* __restrict__ selb, float* __restrict__ rw)
{
    int t = blockIdx.x, lane = threadIdx.x;  // 64 lanes
    float p[NR];
    #pragma unroll
    for (int r = 0; r < NR; ++r) p[r] = 0.f;
    for (int d = lane; d < DM; d += 64) {
        float gv = gate[(size_t)t * DM + d] * 0.001f;
        const float* swr = selw + (size_t)d * NR;
        #pragma unroll
        for (int r = 0; r < NR; ++r) p[r] += gv * swr[r];
    }
    #pragma unroll
    for (int o = 32; o; o >>= 1) {
        #pragma unroll
        for (int r = 0; r < NR; ++r) p[r] += __shfl_down(p[r], o, 64);
    }
    if (lane == 0) {
        float mx = -1e30f;
        #pragma unroll
        for (int r = 0; r < NR; ++r) { p[r] += selb[r]; mx = fmaxf(mx, p[r]); }
        float s = 0.f;
        #pragma unroll
        for (int r = 0; r < NR; ++r) { p[r] = expf(p[r] - mx); s += p[r]; }
        float inv = 1.0f / s;
        #pragma unroll
        for (int r = 0; r < NR; ++r) rw[t * NR + r] = p[r] * inv;
    }
}

// FINAL=0: x = LN(x + sum_slices evp(bf16) + sum_r rw*b2)*g + b -> xout f32 AND xbf
// FINAL=1: xbf = bf16(LN(x)*g + b)
template<int FINAL>
__global__ void ln_kernel(const float* __restrict__ xin, const ushort_t* __restrict__ evp,
                          const float* __restrict__ b2, const float* __restrict__ rwp,
                          const float* __restrict__ g, const float* __restrict__ b,
                          float* __restrict__ xout, ushort_t* __restrict__ xbf)
{
    __shared__ float sA[4], sB[4];
    int row = blockIdx.x, t = row & (T_SEQ - 1);
    int d = threadIdx.x << 1;
    float2 v = *(const float2*)(xin + (size_t)row * DM + d);
    float s0 = v.x, s1 = v.y;
    if (!FINAL) {
        #pragma unroll
        for (int sl = 0; sl < 4; ++sl) {
            unsigned u = ((const unsigned*)(evp + ((size_t)sl * BT + row) * DM))[threadIdx.x];
            s0 += bf2f(u & 0xffffu); s1 += bf2f(u >> 16);
        }
        #pragma unroll
        for (int r = 0; r < NR; ++r) {
            float w = rwp[t * NR + r];
            s0 += w * b2[r * DM + d];
            s1 += w * b2[r * DM + d + 1];
        }
    }
    float sum = s0 + s1, sq = s0 * s0 + s1 * s1;
    #pragma unroll
    for (int o = 32; o; o >>= 1) {
        sum += __shfl_down(sum, o, 64);
        sq  += __shfl_down(sq, o, 64);
    }
    int w = threadIdx.x >> 6;
    if ((threadIdx.x & 63) == 0) { sA[w] = sum; sB[w] = sq; }
    __syncthreads();
    sum = sA[0] + sA[1] + sA[2] + sA[3];
    sq  = sB[0] + sB[1] + sB[2] + sB[3];
    float mean = sum * (1.0f / DM);
    float var  = sq * (1.0f / DM) - mean * mean;
    float rstd = rsqrtf(var + 1e-5f);
    float o0 = (s0 - mean) * rstd * g[d] + b[d];
    float o1 = (s1 - mean) * rstd * g[d + 1] + b[d + 1];
    ushort_t bb[2] = { f2bf(o0), f2bf(o1) };
    ((unsigned*)(xbf + (size_t)row * DM))[threadIdx.x] = *(const unsigned*)bb;
    if (!FINAL)
        *(float2*)(xout + (size_t)row * DM + d) = make_float2(o0, o1);
}

// ---------------------------------------------------------------------------
// 256x256 bf16 GEMM on v_mfma_f32_32x32x16_bf16, BK=64, 8 waves (2x4),
// wave tile 128x64 = 4x2 frags of 32x32 (f32x16 each). 2-phase K-tile:
//   P1: read frag ksteps 0-1 | stage B(t+1) -> BAR -> 16 MFMA -> BAR
//   P2: read frag ksteps 2-3 | lgkmcnt(0) BAR stage A(t+2) -> 16 MFMA
//       -> vmcnt(4 counted / 0 tail) -> BAR
// Loop-top invariant: buffers[cur] ready, outstanding = {A(t+1)} (4 loads).
// C[M,N] = A[M,K] @ Bt[N,K]^T.  AMODE 1: A = xbf[BT][512], K=1536 via row roll.
// Grid: XCD-swizzle -> slice -> 2D groups (nTmG x nTnG, tn-fastest in group).
// EPI 0: Cf[slice]=acc f32.  EPI 1: Cb=bf16(gelu(acc+b1)*rw).  EPI 2: Cb[slice]=bf16(acc).
// ---------------------------------------------------------------------------
template<int EPI, int AMODE>
__global__ __launch_bounds__(512, 2)
void gemm32(const ushort_t* __restrict__ A, const ushort_t* __restrict__ Bt,
            float* __restrict__ Cf, ushort_t* __restrict__ Cb,
            int nTmG, int nTnG, int gridTn, int nPerSlice, int ktiles, int nTnTot,
            int lda, int ldb, int ldc, long long sliceC,
            const float* __restrict__ bias, const float* __restrict__ rwp)
{
    __shared__ ushort_t As[2][256 * 64];
    __shared__ ushort_t Bs[2][256 * 64];

    const int tid  = threadIdx.x;
    const int wave = tid >> 6, lane = tid & 63;
    const int wm = wave >> 2, wn = wave & 3;

    // bijective XCD swizzle (m204)
    int nwg = gridDim.x, bid = blockIdx.x;
    int qq = nwg >> 3, rr = nwg & 7, xc = bid & 7, wi = bid >> 3;
    int wgid = (xc < rr ? xc * (qq + 1) : rr * (qq + 1) + (xc - rr) * qq) + wi;
    int slice = wgid / nPerSlice, rem = wgid - slice * nPerSlice;
    // 2D group mapping: groups of nTmG x nTnG tiles, tn-fastest inside a group
    int gsz = nTmG * nTnG;
    int g = rem / gsz, li = rem - g * gsz;
    int gTn = g % gridTn, gTm = g / gridTn;
    int tm = gTm * nTmG + li / nTnG;
    int tn = gTn * nTnG + li % nTnG;
    if (tn >= nTnTot) return;          // grid padding no-op (uniform per block)

    const int rowBase = tm * 256, colBase = tn * 256;
    const int kbase = slice * ktiles;
    if (EPI == 0) Cf += (long long)slice * sliceC;
    if (EPI == 2) Cb += (long long)slice * sliceC;

    // staging geometry: lane -> row (lane>>3), phys k-slot (lane&7);
    // source k-slot pre-swizzled so reads XOR by (row&7).
    const int lr  = lane >> 3;
    const int skE = (((lane & 7) ^ (lr & 7)) << 3);
    const ushort_t* Bsrc = Bt + (size_t)(colBase + wave * 32 + lr) * ldb + skE;
    const ushort_t* Asrc = A + (size_t)(rowBase + wave * 32 + lr) * lda + skE;

    auto stageA = [&](int t) {
        ushort_t* d = &As[t & 1][wave * 32 * 64];
        if (AMODE == 0) {
            const ushort_t* s = Asrc + (size_t)(kbase + t) * 64;
            #pragma unroll
            for (int j = 0; j < 4; ++j)
                gload16(s + (size_t)(j * 8) * lda, d + j * 512);
        } else {
            int seg  = t >> 3;                                   // 8 k-tiles per 512-segment
            int dts  = (seg == 0) ? 0 : (seg == 1 ? (T_SEQ - 1) : 1);
            int colE = ((t & 7) << 6) + skE;
            #pragma unroll
            for (int j = 0; j < 4; ++j) {
                int gr = rowBase + wave * 32 + j * 8 + lr;
                int sr = (gr & ~(T_SEQ - 1)) | ((gr + dts) & (T_SEQ - 1));
                gload16(A + (size_t)sr * DM + colE, d + j * 512);
            }
        }
    };
    auto stageB = [&](int t) {
        ushort_t* d = &Bs[t & 1][wave * 32 * 64];
        const ushort_t* s = Bsrc + (size_t)(kbase + t) * 64;
        #pragma unroll
        for (int j = 0; j < 4; ++j)
            gload16(s + (size_t)(j * 8) * ldb, d + j * 512);
    };

    // 32x32x16 fragment geometry: lane holds 8 k-contiguous elems at
    // row = base + (lane&31), k-half = lane>>5. 16B slots, phys = s ^ (row&7).
    const int l31 = lane & 31, khalf = lane >> 5;
    const int arow = wm * 128 + l31;
    const int brow = wn * 64 + l31;

    auto ldA = [&](int buf, int mf, int ks) -> bf16x8 {
        int row = arow + mf * 32;
        int slot = (ks * 2 + khalf) ^ (row & 7);
        return *(const bf16x8*)&As[buf][row * 64 + slot * 8];
    };
    auto ldB = [&](int buf, int nf, int ks) -> bf16x8 {
        int row = brow + nf * 32;
        int slot = (ks * 2 + khalf) ^ (row & 7);
        return *(const bf16x8*)&Bs[buf][row * 64 + slot * 8];
    };

    f32x16 acc[4][2] = {};
    bf16x8 a0[4], a1[4], b0[2], b1[2];

    auto mma2 = [&]() {   // two k-steps over the 4x2 frag grid
        #pragma unroll
        for (int mf = 0; mf < 4; ++mf)
            #pragma unroll
            for (int nf = 0; nf < 2; ++nf)
                acc[mf][nf] = __builtin_amdgcn_mfma_f32_32x32x16_bf16(
                    a0[mf], b0[nf], acc[mf][nf], 0, 0, 0);
        #pragma unroll
        for (int mf = 0; mf < 4; ++mf)
            #pragma unroll
            for (int nf = 0; nf < 2; ++nf)
                acc[mf][nf] = __builtin_amdgcn_mfma_f32_32x32x16_bf16(
                    a1[mf], b1[nf], acc[mf][nf], 0, 0, 0);
    };

    // prologue: tile0 (A+B) + tile1's A in flight
    stageA(0); stageB(0);
    if (ktiles > 1) stageA(1);
    VMCNT4();
    BAR();

    for (int t = 0; t < ktiles; ++t) {
        const int cur = t & 1;
        // P1: k-steps 0,1 ; prefetch B(t+1) -> Bs[cur^1]
        #pragma unroll
        for (int mf = 0; mf < 4; ++mf) { a0[mf] = ldA(cur, mf, 0); a1[mf] = ldA(cur, mf, 1); }
        #pragma unroll
        for (int nf = 0; nf < 2; ++nf) { b0[nf] = ldB(cur, nf, 0); b1[nf] = ldB(cur, nf, 1); }
        if (t + 1 < ktiles) stageB(t + 1);
        BAR();
        __builtin_amdgcn_s_setprio(1); mma2(); __builtin_amdgcn_s_setprio(0);
        BAR();
        // P2: k-steps 2,3 ; prefetch A(t+2) -> As[cur] after a read fence
        #pragma unroll
        for (int mf = 0; mf < 4; ++mf) { a0[mf] = ldA(cur, mf, 2); a1[mf] = ldA(cur, mf, 3); }
        #pragma unroll
        for (int nf = 0; nf < 2; ++nf) { b0[nf] = ldB(cur, nf, 2); b1[nf] = ldB(cur, nf, 3); }
        bool pre = (t + 2 < ktiles);
        if (pre) {
            LGKM0();          // all my As[cur] reads retired
            BAR();            // ... and everyone else's
            stageA(t + 2);
        }
        __builtin_amdgcn_s_setprio(1); mma2(); __builtin_amdgcn_s_setprio(0);
        if (pre) { VMCNT4(); } else { VMCNT0(); }   // tile t+1 fully landed
        BAR();
    }

    // epilogue: C/D layout (m74/m101): col = lane&31, row = (r&3)+8*(r>>2)+4*(lane>>5)
    if constexpr (EPI == 0) {
        #pragma unroll
        for (int mf = 0; mf < 4; ++mf)
            #pragma unroll
            for (int nf = 0; nf < 2; ++nf) {
                int gc = colBase + wn * 64 + nf * 32 + l31;
                int rb = rowBase + wm * 128 + mf * 32 + 4 * khalf;
                #pragma unroll
                for (int r = 0; r < 16; ++r) {
                    int grow = rb + (r & 3) + ((r >> 2) << 3);
                    Cf[(size_t)grow * ldc + gc] = acc[mf][nf][r];
                }
            }
    } else if constexpr (EPI == 2) {
        #pragma unroll
        for (int mf = 0; mf < 4; ++mf)
            #pragma unroll
            for (int nf = 0; nf < 2; ++nf) {
                int gc = colBase + wn * 64 + nf * 32 + l31;
                int rb = rowBase + wm * 128 + mf * 32 + 4 * khalf;
                #pragma unroll
                for (int r = 0; r < 16; ++r) {
                    int grow = rb + (r & 3) + ((r >> 2) << 3);
                    Cb[(size_t)grow * ldc + gc] = f2bf(acc[mf][nf][r]);
                }
            }
    } else {
        #pragma unroll
        for (int mf = 0; mf < 4; ++mf)
            #pragma unroll
            for (int nf = 0; nf < 2; ++nf) {
                int cb = colBase + wn * 64 + nf * 32;
                int gc = cb + l31;
                int rule = cb >> 10;               // 32-col span within one rule
                float bv = bias[rule * H2 + (gc & (H2 - 1))];
                int rb = rowBase + wm * 128 + mf * 32 + 4 * khalf;
                #pragma unroll
                for (int r = 0; r < 16; ++r) {
                    int grow = rb + (r & 3) + ((r >> 2) << 3);
                    float v = acc[mf][nf][r] + bv;
                    v = gelu_fast(v) * rwp[(grow & (T_SEQ - 1)) * NR + rule];
                    Cb[(size_t)grow * ldc + gc] = f2bf(v);
                }
            }
    }
}

extern "C" void kernel_launch(void* const* d_in, const int* in_sizes, int n_in,
                              void* d_out, int out_size, void* d_ws, size_t ws_size,
                              hipStream_t stream)
{
    const int*   tokens = (const int*)d_in[0];
    const float* gate   = (const float*)d_in[1];
    const float* emb    = (const float*)d_in[2];
    const float* pos    = (const float*)d_in[3];
    const float* w1     = (const float*)d_in[4];
    const float* b1     = (const float*)d_in[5];
    const float* w2     = (const float*)d_in[6];
    const float* b2     = (const float*)d_in[7];
    const float* selw   = (const float*)d_in[8];
    const float* selb   = (const float*)d_in[9];
    const float* ng     = (const float*)d_in[10];
    const float* nbm    = (const float*)d_in[11];
    const float* lnfg   = (const float*)d_in[12];
    const float* lnfb   = (const float*)d_in[13];
    const float* headw  = (const float*)d_in[14];
    float* out = (float*)d_out;
    (void)in_sizes; (void)n_in; (void)out_size; (void)ws_size;

    size_t off = 0;
    auto alloc = [&](size_t bytes) {
        void* p = (char*)d_ws + off;
        off += (bytes + 255) & ~(size_t)255;
        return p;
    };
    float*    x   = (float*)alloc((size_t)BT * DM * 4);
    ushort_t* xbf = (ushort_t*)alloc((size_t)BT * DM * 2);
    ushort_t* evp = (ushort_t*)alloc((size_t)4 * BT * DM * 2);
    ushort_t* W1t = (ushort_t*)alloc((size_t)NR * H2 * K1 * 2);
    ushort_t* W2t = (ushort_t*)alloc((size_t)DM * HN * 2);
    ushort_t* HWt = (ushort_t*)alloc((size_t)VSZ * DM * 2);
    float*    rw  = (float*)alloc((size_t)T_SEQ * NR * 4);
    ushort_t* H   = (ushort_t*)alloc((size_t)BT * HN * 2);

    // --- weight conversion / transpose ---
    transpose_f32_bf16<<<dim3(H2 / 32, K1 / 32, NR), dim3(32, 8), 0, stream>>>(
        w1, W1t, K1, H2, (long long)K1 * H2, (long long)H2 * K1, K1);
    transpose_f32_bf16<<<dim3(DM / 32, H2 / 32, NR), dim3(32, 8), 0, stream>>>(
        w2, W2t, H2, DM, (long long)H2 * DM, (long long)H2, HN);
    transpose_f32_bf16<<<dim3(VSZ / 32, DM / 32, 1), dim3(32, 8), 0, stream>>>(
        headw, HWt, DM, VSZ, 0LL, 0LL, DM);

    // --- x = embed + pos (f32 + bf16); rule weights ---
    embed_pos<<<dim3(BT), dim3(256), 0, stream>>>(tokens, emb, pos, x, xbf);
    rw_kernel<<<dim3(T_SEQ), dim3(64), 0, stream>>>(gate, selw, selb, rw);

    // --- 5 CA steps ---
    for (int s = 0; s < NSTEP; ++s) {
        // GEMM1: H = bf16(gelu(NB @ W1 + b1) * rw), NB synthesized from xbf via roll.
        // tiles 32x32, groups 8x8 (gridTn=4)
        gemm32<1, 1><<<dim3(1024), dim3(512), 0, stream>>>(
            xbf, W1t, nullptr, H, 8, 8, 4, 1024, K1 / 64, 32,
            DM, K1, HN, 0LL, b1, rw);
        // GEMM2: evp[slice] = bf16(H @ W2) (split-K x4); tiles 32x2, groups 8x2 (gridTn=1)
        gemm32<2, 0><<<dim3(256), dim3(512), 0, stream>>>(
            H, W2t, nullptr, evp, 8, 2, 1, 64, HN / 64 / 4, 2,
            HN, HN, DM, (long long)BT * DM, nullptr, nullptr);
        ln_kernel<0><<<dim3(BT), dim3(256), 0, stream>>>(
            x, evp, b2, rw, ng + s * DM, nbm + s * DM, x, xbf);
    }

    // --- final LN -> bf16, head GEMM -> f32 out ---
    ln_kernel<1><<<dim3(BT), dim3(256), 0, stream>>>(
        x, nullptr, nullptr, nullptr, lnfg, lnfb, nullptr, xbf);
    // head: tiles 32x125 (padded to 128), groups 8x8 (gridTn=16), grid 4096
    gemm32<0, 0><<<dim3(4096), dim3(512), 0, stream>>>(
        xbf, HWt, out, nullptr, 8, 8, 16, 4096, DM / 64, 125,
        DM, DM, VSZ, 0LL, nullptr, nullptr);
}

// Round 6
// 2048.418 us; speedup vs baseline: 1.0364x; 1.0364x over previous
//
#include <hip/hip_runtime.h>

#define T_SEQ 2048
#define BT    8192
#define DM    512
#define NR    8
#define NSTEP 5
#define K1    1536   // 3*D
#define H2    1024   // 2*D
#define VSZ   32000
#define HN    8192   // NR*H2

using ushort_t = unsigned short;
using bf16x8 = __attribute__((ext_vector_type(8))) __bf16;
using f32x4  = __attribute__((ext_vector_type(4))) float;

__device__ __forceinline__ ushort_t f2bf(float f) {
    union { float f; unsigned u; } v; v.f = f;
    unsigned r = v.u + 0x7FFFu + ((v.u >> 16) & 1u);
    return (ushort_t)(r >> 16);
}

__device__ __forceinline__ float bf2f(unsigned hi) {
    union { unsigned u; float f; } v; v.u = hi << 16;
    return v.f;
}

__device__ __forceinline__ void gload16(const void* g, void* l) {
    __builtin_amdgcn_global_load_lds((const __attribute__((address_space(1))) void*)g,
                                     (__attribute__((address_space(3))) void*)l, 16, 0, 0);
}

// gelu(tanh form) = x * sigmoid(x*(2.3022861 + 0.10294456*x^2))  [exact identity]
__device__ __forceinline__ float gelu_fast(float x) {
    float x2 = x * x;
    float u  = x * fmaf(x2, 0.10294456f, 2.3022861f);   // 2y*log2(e)
    float e  = exp2f(-u);
    return x * __builtin_amdgcn_rcpf(1.0f + e);
}

#define BAR()     __builtin_amdgcn_s_barrier()
#define VMCNT4()  asm volatile("s_waitcnt vmcnt(4)" ::: "memory")
#define VMCNT0()  asm volatile("s_waitcnt vmcnt(0)" ::: "memory")
#define LGKM0()   asm volatile("s_waitcnt lgkmcnt(0)" ::: "memory")

// transpose f32 src[z][K][N] -> bf16 dst[z*dstBatch + n*dstRow + k]
__global__ void transpose_f32_bf16(const float* __restrict__ src, ushort_t* __restrict__ dst,
                                   int K, int N, long long srcBatch, long long dstBatch, int dstRow)
{
    __shared__ float tile[32][33];
    src += (size_t)blockIdx.z * srcBatch;
    dst += (size_t)blockIdx.z * dstBatch;
    int n0 = blockIdx.x * 32, k0 = blockIdx.y * 32;
    int tx = threadIdx.x, ty = threadIdx.y;
    #pragma unroll
    for (int i = 0; i < 32; i += 8)
        tile[ty + i][tx] = src[(size_t)(k0 + ty + i) * N + (n0 + tx)];
    __syncthreads();
    #pragma unroll
    for (int i = 0; i < 32; i += 8)
        dst[(size_t)(n0 + ty + i) * dstRow + (k0 + tx)] = f2bf(tile[tx][ty + i]);
}

__global__ void embed_pos(const int* __restrict__ tokens, const float* __restrict__ emb,
                          const float* __restrict__ pos, float* __restrict__ x,
                          ushort_t* __restrict__ xbf)
{
    int row = blockIdx.x;
    int t = row & (T_SEQ - 1);
    int tok = tokens[row];
    int i = threadIdx.x;              // 256 threads * float2 = 512 floats
    float2 e = ((const float2*)(emb + (size_t)tok * DM))[i];
    float2 p = ((const float2*)(pos + (size_t)t * DM))[i];
    float2 v = make_float2(e.x + p.x, e.y + p.y);
    ((float2*)(x + (size_t)row * DM))[i] = v;
    ushort_t bb[2] = { f2bf(v.x), f2bf(v.y) };
    ((unsigned*)(xbf + (size_t)row * DM))[i] = *(const unsigned*)bb;
}

__global__ void rw_kernel(const float* __restrict__ gate, const float* __restrict__ selw,
                          const float* __restrict__ selb, float* __restrict__ rw)
{
    int t = blockIdx.x, lane = threadIdx.x;  // 64 lanes
    float p[NR];
    #pragma unroll
    for (int r = 0; r < NR; ++r) p[r] = 0.f;
    for (int d = lane; d < DM; d += 64) {
        float gv = gate[(size_t)t * DM + d] * 0.001f;
        const float* swr = selw + (size_t)d * NR;
        #pragma unroll
        for (int r = 0; r < NR; ++r) p[r] += gv * swr[r];
    }
    #pragma unroll
    for (int o = 32; o; o >>= 1) {
        #pragma unroll
        for (int r = 0; r < NR; ++r) p[r] += __shfl_down(p[r], o, 64);
    }
    if (lane == 0) {
        float mx = -1e30f;
        #pragma unroll
        for (int r = 0; r < NR; ++r) { p[r] += selb[r]; mx = fmaxf(mx, p[r]); }
        float s = 0.f;
        #pragma unroll
        for (int r = 0; r < NR; ++r) { p[r] = expf(p[r] - mx); s += p[r]; }
        float inv = 1.0f / s;
        #pragma unroll
        for (int r = 0; r < NR; ++r) rw[t * NR + r] = p[r] * inv;
    }
}

// FINAL=0: x = LN(x + sum_slices evp(bf16) + sum_r rw*b2)*g + b -> xout f32 AND xbf
// FINAL=1: xbf = bf16(LN(x)*g + b)
template<int FINAL>
__global__ void ln_kernel(const float* __restrict__ xin, const ushort_t* __restrict__ evp,
                          const float* __restrict__ b2, const float* __restrict__ rwp,
                          const float* __restrict__ g, const float* __restrict__ b,
                          float* __restrict__ xout, ushort_t* __restrict__ xbf)
{
    __shared__ float sA[4], sB[4];
    int row = blockIdx.x, t = row & (T_SEQ - 1);
    int d = threadIdx.x << 1;
    float2 v = *(const float2*)(xin + (size_t)row * DM + d);
    float s0 = v.x, s1 = v.y;
    if (!FINAL) {
        #pragma unroll
        for (int sl = 0; sl < 4; ++sl) {
            unsigned u = ((const unsigned*)(evp + ((size_t)sl * BT + row) * DM))[threadIdx.x];
            s0 += bf2f(u & 0xffffu); s1 += bf2f(u >> 16);
        }
        #pragma unroll
        for (int r = 0; r < NR; ++r) {
            float w = rwp[t * NR + r];
            s0 += w * b2[r * DM + d];
            s1 += w * b2[r * DM + d + 1];
        }
    }
    float sum = s0 + s1, sq = s0 * s0 + s1 * s1;
    #pragma unroll
    for (int o = 32; o; o >>= 1) {
        sum += __shfl_down(sum, o, 64);
        sq  += __shfl_down(sq, o, 64);
    }
    int w = threadIdx.x >> 6;
    if ((threadIdx.x & 63) == 0) { sA[w] = sum; sB[w] = sq; }
    __syncthreads();
    sum = sA[0] + sA[1] + sA[2] + sA[3];
    sq  = sB[0] + sB[1] + sB[2] + sB[3];
    float mean = sum * (1.0f / DM);
    float var  = sq * (1.0f / DM) - mean * mean;
    float rstd = rsqrtf(var + 1e-5f);
    float o0 = (s0 - mean) * rstd * g[d] + b[d];
    float o1 = (s1 - mean) * rstd * g[d + 1] + b[d + 1];
    ushort_t bb[2] = { f2bf(o0), f2bf(o1) };
    ((unsigned*)(xbf + (size_t)row * DM))[threadIdx.x] = *(const unsigned*)bb;
    if (!FINAL)
        *(float2*)(xout + (size_t)row * DM + d) = make_float2(o0, o1);
}

// ---------------------------------------------------------------------------
// 256x256 bf16 GEMM, 16x16x32 MFMA, BK=64, 8 waves (2 wm x 4 wn).
// Faithful m201-style 4-phase K-tile; one counted vmcnt(4) per tile.
//   P1: read A[mh0](8)+B[nh0](4) | stage Bh0(t+1) | BAR lgkm0 16-MFMA(0,0) BAR
//   P2: read B[nh1](4)           | stage Bh1(t+1) | BAR lgkm0 16-MFMA(0,1) BAR
//   P3: read A[mh1](8)           | stage A(t+2) by waves{0,1,4,5} (mh0 rows)
//                                                 | BAR lgkm0 16-MFMA(1,1) BAR
//   P4: stage A(t+2) by waves{2,3,6,7} (mh1 rows) | 16-MFMA(1,0) vmcnt(4) BAR
// Ledger (per wave, issue order monotone in need-time):
//   groupX: [A(t+1)4, Bh0 2, Bh1 2, A(t+2)4] -> vmcnt(4) keeps A(t+2)
//   groupY: [A(t+1)4, Bh0 2, Bh1 2, A(t+2)4] -> same
// Tail (t+2>=ktiles): vmcnt(0) drains B(t+1).
// Race audit: A(t+2)->As[cur] mh0 rows staged P3 (mh0 last read P1, retired
// in-order before P1's MFMA, cross-wave via P1/P2 barriers); mh1 rows staged
// P4 (last read P3). B(t+1)->Bs[cur^1] never read during tile t.
// C[M,N] = A[M,K] @ Bt[N,K]^T.  AMODE 1: A = xbf[BT][512], K=1536 via row roll.
// FASTM 1: tm fastest (B-panel shared per XCD).
// EPI 0: Cf[slice]=acc f32.  EPI 1: Cb=bf16(gelu(acc+b1)*rw).  EPI 2: Cb[slice]=bf16(acc).
// ---------------------------------------------------------------------------
template<int EPI, int AMODE, int FASTM>
__global__ __launch_bounds__(512, 2)
void gemm4p(const ushort_t* __restrict__ A, const ushort_t* __restrict__ Bt,
            float* __restrict__ Cf, ushort_t* __restrict__ Cb,
            int nTileFast, int nPerSlice, int ktiles,
            int lda, int ldb, int ldc, long long sliceC,
            const float* __restrict__ bias, const float* __restrict__ rwp)
{
    __shared__ ushort_t As[2][256 * 64];
    __shared__ ushort_t Bs[2][256 * 64];

    const int tid  = threadIdx.x;
    const int wave = tid >> 6, lane = tid & 63;
    const int wm = wave >> 2, wn = wave & 3;

    // bijective XCD swizzle (m204)
    int nwg = gridDim.x, bid = blockIdx.x;
    int qq = nwg >> 3, rr = nwg & 7, xc = bid & 7, wi = bid >> 3;
    int wgid = (xc < rr ? xc * (qq + 1) : rr * (qq + 1) + (xc - rr) * qq) + wi;
    int slice = wgid / nPerSlice, rem = wgid - slice * nPerSlice;
    int tA = rem / nTileFast, tB = rem - tA * nTileFast;
    int tm = FASTM ? tB : tA, tn = FASTM ? tA : tB;
    const int rowBase = tm * 256, colBase = tn * 256;
    const int kbase = slice * ktiles;
    if (EPI == 0) Cf += (long long)slice * sliceC;
    if (EPI == 2) Cb += (long long)slice * sliceC;

    // staging geometry: lane -> row (lane>>3), phys k-slot (lane&7);
    // source k-slot pre-swizzled so reads XOR by (row&7).
    const int lr  = lane >> 3;
    const int skE = (((lane & 7) ^ (lr & 7)) << 3);
    const ushort_t* Bsrc = Bt + (size_t)(colBase + wave * 32 + lr) * ldb + skE;
    const ushort_t* Asrc = A + (size_t)(rowBase + wave * 32 + lr) * lda + skE;

    // stage one 8-row chunk j (j=0..3) of this wave's 32-row strip
    auto stageAj = [&](int t, int j) {
        ushort_t* d = &As[t & 1][wave * 32 * 64 + j * 512];
        if (AMODE == 0) {
            gload16(Asrc + (size_t)(kbase + t) * 64 + (size_t)(j * 8) * lda, d);
        } else {
            int seg  = t >> 3;                                   // 8 k-tiles per 512-segment
            int dts  = (seg == 0) ? 0 : (seg == 1 ? (T_SEQ - 1) : 1);
            int colE = ((t & 7) << 6) + skE;
            int gr = rowBase + wave * 32 + j * 8 + lr;
            int sr = (gr & ~(T_SEQ - 1)) | ((gr + dts) & (T_SEQ - 1));
            gload16(A + (size_t)sr * DM + colE, d);
        }
    };
    auto stageA4 = [&](int t) {
        #pragma unroll
        for (int j = 0; j < 4; ++j) stageAj(t, j);
    };
    auto stageBh = [&](int t, int h) {   // half-strip: chunks 2h, 2h+1
        ushort_t* d = &Bs[t & 1][wave * 32 * 64];
        const ushort_t* s = Bsrc + (size_t)(kbase + t) * 64;
        #pragma unroll
        for (int j = 2 * h; j < 2 * h + 2; ++j)
            gload16(s + (size_t)(j * 8) * ldb, d + j * 512);
    };

    // MFMA fragment read geometry (16x16x32)
    const int l15 = lane & 15;
    const int sl0 = (((lane >> 4) ^ (lane & 7))) << 3;       // kstep0 slot offset (elems)
    const int sl1 = (((lane >> 4) + 4) ^ (lane & 7)) << 3;   // kstep1
    const int aoff = (wm * 128 + l15) * 64;
    const int boff = (wn * 64 + l15) * 64;

    f32x4 acc[8][4] = {};
    bf16x8 Ar[2][4];        // current mh: [kstep][m]
    bf16x8 Br[2][2][2];     // [nh][kstep][n] (nh0 reused in P4)

    auto readA = [&](int buf, int mh) {
        #pragma unroll
        for (int m = 0; m < 4; ++m) {
            int base = aoff + mh * 4096 + m * 1024;
            Ar[0][m] = *(const bf16x8*)&As[buf][base + sl0];
            Ar[1][m] = *(const bf16x8*)&As[buf][base + sl1];
        }
    };
    auto readB = [&](int buf, int nh) {
        #pragma unroll
        for (int n = 0; n < 2; ++n) {
            int base = boff + nh * 2048 + n * 1024;
            Br[nh][0][n] = *(const bf16x8*)&Bs[buf][base + sl0];
            Br[nh][1][n] = *(const bf16x8*)&Bs[buf][base + sl1];
        }
    };
    auto mmaQ = [&](int mh, int nh) {
        __builtin_amdgcn_s_setprio(1);
        #pragma unroll
        for (int k = 0; k < 2; ++k)
            #pragma unroll
            for (int m = 0; m < 4; ++m)
                #pragma unroll
                for (int n = 0; n < 2; ++n)
                    acc[mh * 4 + m][nh * 2 + n] = __builtin_amdgcn_mfma_f32_16x16x32_bf16(
                        Ar[k][m], Br[nh][k][n], acc[mh * 4 + m][nh * 2 + n], 0, 0, 0);
        __builtin_amdgcn_s_setprio(0);
    };

    // prologue: A(0), B(0) full; A(1) full kept in flight
    stageA4(0); stageBh(0, 0); stageBh(0, 1);
    if (ktiles > 1) { stageA4(1); VMCNT4(); } else { VMCNT0(); }
    BAR();

    const bool grpX = !(wave & 2);       // waves 0,1,4,5: strips in mh0 rows

    for (int t = 0; t < ktiles; ++t) {
        const int cur = t & 1;
        const bool preB = (t + 1 < ktiles);
        const bool preA = (t + 2 < ktiles);
        // P1: A[mh0] + B[nh0]; stage Bh0(t+1)
        readA(cur, 0); readB(cur, 0);
        if (preB) stageBh(t + 1, 0);
        BAR(); LGKM0();
        mmaQ(0, 0);
        BAR();
        // P2: B[nh1]; stage Bh1(t+1)
        readB(cur, 1);
        if (preB) stageBh(t + 1, 1);
        BAR(); LGKM0();
        mmaQ(0, 1);
        BAR();
        // P3: A[mh1]; stage A(t+2) for group-X waves (their strips = mh0 rows,
        // last read in P1, retired before P1's MFMA; cross-wave via barriers)
        readA(cur, 1);
        if (preA && grpX) stageA4(t + 2);
        BAR(); LGKM0();
        mmaQ(1, 1);
        BAR();
        // P4: stage A(t+2) for group-Y waves (mh1 rows, last read P3); pure MFMA
        if (preA && !grpX) stageA4(t + 2);
        mmaQ(1, 0);
        if (preA) { VMCNT4(); } else { VMCNT0(); }
        BAR();
    }

    // epilogue
    const int cl = l15, rl = (lane >> 4) << 2;
    if constexpr (EPI == 0) {
        #pragma unroll
        for (int mf = 0; mf < 8; ++mf) {
            int gr = rowBase + wm * 128 + mf * 16 + rl;
            #pragma unroll
            for (int nf = 0; nf < 4; ++nf) {
                int gc = colBase + wn * 64 + nf * 16 + cl;
                #pragma unroll
                for (int i = 0; i < 4; ++i)
                    Cf[(size_t)(gr + i) * ldc + gc] = acc[mf][nf][i];
            }
        }
    } else if constexpr (EPI == 2) {
        #pragma unroll
        for (int mf = 0; mf < 8; ++mf) {
            int gr = rowBase + wm * 128 + mf * 16 + rl;
            #pragma unroll
            for (int nf = 0; nf < 4; ++nf) {
                int gc = colBase + wn * 64 + nf * 16 + cl;
                #pragma unroll
                for (int i = 0; i < 4; ++i)
                    Cb[(size_t)(gr + i) * ldc + gc] = f2bf(acc[mf][nf][i]);
            }
        }
    } else {
        int r = (colBase + wn * 64) >> 10;   // 64-col span never crosses a rule boundary
        float bv[4];
        #pragma unroll
        for (int nf = 0; nf < 4; ++nf)
            bv[nf] = bias[r * H2 + ((colBase + wn * 64 + nf * 16 + cl) & (H2 - 1))];
        #pragma unroll
        for (int mf = 0; mf < 8; ++mf) {
            int gr = rowBase + wm * 128 + mf * 16 + rl;
            #pragma unroll
            for (int i = 0; i < 4; ++i) {
                float rwv = rwp[((gr + i) & (T_SEQ - 1)) * NR + r];
                #pragma unroll
                for (int nf = 0; nf < 4; ++nf) {
                    int gc = colBase + wn * 64 + nf * 16 + cl;
                    float v = acc[mf][nf][i] + bv[nf];
                    v = gelu_fast(v) * rwv;
                    Cb[(size_t)gr * ldc + (size_t)i * ldc + gc] = f2bf(v);
                }
            }
        }
    }
}

extern "C" void kernel_launch(void* const* d_in, const int* in_sizes, int n_in,
                              void* d_out, int out_size, void* d_ws, size_t ws_size,
                              hipStream_t stream)
{
    const int*   tokens = (const int*)d_in[0];
    const float* gate   = (const float*)d_in[1];
    const float* emb    = (const float*)d_in[2];
    const float* pos    = (const float*)d_in[3];
    const float* w1     = (const float*)d_in[4];
    const float* b1     = (const float*)d_in[5];
    const float* w2     = (const float*)d_in[6];
    const float* b2     = (const float*)d_in[7];
    const float* selw   = (const float*)d_in[8];
    const float* selb   = (const float*)d_in[9];
    const float* ng     = (const float*)d_in[10];
    const float* nbm    = (const float*)d_in[11];
    const float* lnfg   = (const float*)d_in[12];
    const float* lnfb   = (const float*)d_in[13];
    const float* headw  = (const float*)d_in[14];
    float* out = (float*)d_out;
    (void)in_sizes; (void)n_in; (void)out_size; (void)ws_size;

    size_t off = 0;
    auto alloc = [&](size_t bytes) {
        void* p = (char*)d_ws + off;
        off += (bytes + 255) & ~(size_t)255;
        return p;
    };
    float*    x   = (float*)alloc((size_t)BT * DM * 4);
    ushort_t* xbf = (ushort_t*)alloc((size_t)BT * DM * 2);
    ushort_t* evp = (ushort_t*)alloc((size_t)4 * BT * DM * 2);
    ushort_t* W1t = (ushort_t*)alloc((size_t)NR * H2 * K1 * 2);
    ushort_t* W2t = (ushort_t*)alloc((size_t)DM * HN * 2);
    ushort_t* HWt = (ushort_t*)alloc((size_t)VSZ * DM * 2);
    float*    rw  = (float*)alloc((size_t)T_SEQ * NR * 4);
    ushort_t* H   = (ushort_t*)alloc((size_t)BT * HN * 2);

    // --- weight conversion / transpose ---
    transpose_f32_bf16<<<dim3(H2 / 32, K1 / 32, NR), dim3(32, 8), 0, stream>>>(
        w1, W1t, K1, H2, (long long)K1 * H2, (long long)H2 * K1, K1);
    transpose_f32_bf16<<<dim3(DM / 32, H2 / 32, NR), dim3(32, 8), 0, stream>>>(
        w2, W2t, H2, DM, (long long)H2 * DM, (long long)H2, HN);
    transpose_f32_bf16<<<dim3(VSZ / 32, DM / 32, 1), dim3(32, 8), 0, stream>>>(
        headw, HWt, DM, VSZ, 0LL, 0LL, DM);

    // --- x = embed + pos (f32 + bf16); rule weights ---
    embed_pos<<<dim3(BT), dim3(256), 0, stream>>>(tokens, emb, pos, x, xbf);
    rw_kernel<<<dim3(T_SEQ), dim3(64), 0, stream>>>(gate, selw, selb, rw);

    // --- 5 CA steps ---
    for (int s = 0; s < NSTEP; ++s) {
        // GEMM1: H = bf16(gelu(NB @ W1 + b1) * rw), NB synthesized from xbf via roll.
        // FASTM=1: concurrent blocks per XCD share a B-panel, stream xbf once.
        gemm4p<1, 1, 1><<<dim3(1024), dim3(512), 0, stream>>>(
            xbf, W1t, nullptr, H, /*nTileFast(tm)*/32, /*nPerSlice*/1024, /*ktiles*/K1 / 64,
            DM, K1, HN, 0LL, b1, rw);
        // GEMM2: evp[slice] = bf16(H @ W2) (split-K x4)
        gemm4p<2, 0, 0><<<dim3(256), dim3(512), 0, stream>>>(
            H, W2t, nullptr, evp, /*nTileFast(tn)*/2, /*nPerSlice*/64, /*ktiles*/HN / 64 / 4,
            HN, HN, DM, (long long)BT * DM, nullptr, nullptr);
        ln_kernel<0><<<dim3(BT), dim3(256), 0, stream>>>(
            x, evp, b2, rw, ng + s * DM, nbm + s * DM, x, xbf);
    }

    // --- final LN -> bf16, head GEMM -> f32 out ---
    ln_kernel<1><<<dim3(BT), dim3(256), 0, stream>>>(
        x, nullptr, nullptr, nullptr, lnfg, lnfb, nullptr, xbf);
    gemm4p<0, 0, 0><<<dim3(4000), dim3(512), 0, stream>>>(
        xbf, HWt, out, nullptr, /*nTileFast(tn)*/125, /*nPerSlice*/4000, /*ktiles*/DM / 64,
        DM, DM, VSZ, 0LL, nullptr, nullptr);
}

// Round 7
// 1948.324 us; speedup vs baseline: 1.0896x; 1.0514x over previous
//
#include <hip/hip_runtime.h>

#define T_SEQ 2048
#define BT    8192
#define DM    512
#define NR    8
#define NSTEP 5
#define K1    1536   // 3*D
#define H2    1024   // 2*D
#define VSZ   32000
#define HN    8192   // NR*H2

using ushort_t = unsigned short;
using bf16x8 = __attribute__((ext_vector_type(8))) __bf16;
using f32x4  = __attribute__((ext_vector_type(4))) float;

__device__ __forceinline__ ushort_t f2bf(float f) {
    union { float f; unsigned u; } v; v.f = f;
    unsigned r = v.u + 0x7FFFu + ((v.u >> 16) & 1u);
    return (ushort_t)(r >> 16);
}

__device__ __forceinline__ float bf2f(unsigned hi) {
    union { unsigned u; float f; } v; v.u = hi << 16;
    return v.f;
}

__device__ __forceinline__ void gload16(const void* g, void* l) {
    __builtin_amdgcn_global_load_lds((const __attribute__((address_space(1))) void*)g,
                                     (__attribute__((address_space(3))) void*)l, 16, 0, 0);
}

// gelu(tanh form) = x * sigmoid(x*(2.3022861 + 0.10294456*x^2))  [exact identity]
__device__ __forceinline__ float gelu_fast(float x) {
    float x2 = x * x;
    float u  = x * fmaf(x2, 0.10294456f, 2.3022861f);   // 2y*log2(e)
    float e  = exp2f(-u);
    return x * __builtin_amdgcn_rcpf(1.0f + e);
}

#define BAR()    __builtin_amdgcn_s_barrier()
#define VMCNT4() asm volatile("s_waitcnt vmcnt(4)" ::: "memory")
#define VMCNT0() asm volatile("s_waitcnt vmcnt(0)" ::: "memory")

// transpose f32 src[z][K][N] -> bf16 dst[z*dstBatch + n*dstRow + k]
__global__ void transpose_f32_bf16(const float* __restrict__ src, ushort_t* __restrict__ dst,
                                   int K, int N, long long srcBatch, long long dstBatch, int dstRow)
{
    __shared__ float tile[32][33];
    src += (size_t)blockIdx.z * srcBatch;
    dst += (size_t)blockIdx.z * dstBatch;
    int n0 = blockIdx.x * 32, k0 = blockIdx.y * 32;
    int tx = threadIdx.x, ty = threadIdx.y;
    #pragma unroll
    for (int i = 0; i < 32; i += 8)
        tile[ty + i][tx] = src[(size_t)(k0 + ty + i) * N + (n0 + tx)];
    __syncthreads();
    #pragma unroll
    for (int i = 0; i < 32; i += 8)
        dst[(size_t)(n0 + ty + i) * dstRow + (k0 + tx)] = f2bf(tile[tx][ty + i]);
}

__global__ void embed_pos(const int* __restrict__ tokens, const float* __restrict__ emb,
                          const float* __restrict__ pos, float* __restrict__ x,
                          ushort_t* __restrict__ xbf)
{
    int row = blockIdx.x;
    int t = row & (T_SEQ - 1);
    int tok = tokens[row];
    int i = threadIdx.x;              // 256 threads * float2 = 512 floats
    float2 e = ((const float2*)(emb + (size_t)tok * DM))[i];
    float2 p = ((const float2*)(pos + (size_t)t * DM))[i];
    float2 v = make_float2(e.x + p.x, e.y + p.y);
    ((float2*)(x + (size_t)row * DM))[i] = v;
    ushort_t bb[2] = { f2bf(v.x), f2bf(v.y) };
    ((unsigned*)(xbf + (size_t)row * DM))[i] = *(const unsigned*)bb;
}

// rw[t,r] softmax + b2rw[t,d] = sum_r rw[t,r]*b2[r,d]   (step-invariant)
__global__ void rw_kernel(const float* __restrict__ gate, const float* __restrict__ selw,
                          const float* __restrict__ selb, const float* __restrict__ b2,
                          float* __restrict__ rw, float* __restrict__ b2rw)
{
    int t = blockIdx.x, lane = threadIdx.x;  // 64 lanes
    float p[NR];
    #pragma unroll
    for (int r = 0; r < NR; ++r) p[r] = 0.f;
    for (int d = lane; d < DM; d += 64) {
        float gv = gate[(size_t)t * DM + d] * 0.001f;
        const float* swr = selw + (size_t)d * NR;
        #pragma unroll
        for (int r = 0; r < NR; ++r) p[r] += gv * swr[r];
    }
    #pragma unroll
    for (int o = 32; o; o >>= 1) {
        #pragma unroll
        for (int r = 0; r < NR; ++r) p[r] += __shfl_xor(p[r], o, 64);
    }
    float mx = -1e30f;
    #pragma unroll
    for (int r = 0; r < NR; ++r) { p[r] += selb[r]; mx = fmaxf(mx, p[r]); }
    float s = 0.f;
    #pragma unroll
    for (int r = 0; r < NR; ++r) { p[r] = expf(p[r] - mx); s += p[r]; }
    float inv = 1.0f / s;
    #pragma unroll
    for (int r = 0; r < NR; ++r) p[r] *= inv;
    if (lane < NR) rw[t * NR + lane] = p[lane];
    #pragma unroll
    for (int it = 0; it < DM / 64; ++it) {
        int d = it * 64 + lane;
        float a = 0.f;
        #pragma unroll
        for (int r = 0; r < NR; ++r) a += p[r] * b2[r * DM + d];
        b2rw[(size_t)t * DM + d] = a;
    }
}

// Row-per-wave LN. MODE 0: x = LN(x + sum_sl evp + b2rw)*g + b -> x f32 + xbf.
// MODE 2: v = LN(x + sum_sl evp + b2rw)*g + b; xbf = bf16(LN(v)*fg + fb)  (fused final)
template<int MODE>
__global__ __launch_bounds__(256)
void ln_kernel(const float* __restrict__ xin, const ushort_t* __restrict__ evp,
               const float* __restrict__ b2rw,
               const float* __restrict__ g, const float* __restrict__ b,
               const float* __restrict__ fg, const float* __restrict__ fb,
               float* __restrict__ xout, ushort_t* __restrict__ xbf)
{
    int row = (blockIdx.x << 2) + (threadIdx.x >> 6);
    int lane = threadIdx.x & 63;
    int t = row & (T_SEQ - 1);
    int d0 = lane << 3;

    float s[8];
    {
        float4 a = *(const float4*)(xin + (size_t)row * DM + d0);
        float4 c = *(const float4*)(xin + (size_t)row * DM + d0 + 4);
        s[0]=a.x; s[1]=a.y; s[2]=a.z; s[3]=a.w; s[4]=c.x; s[5]=c.y; s[6]=c.z; s[7]=c.w;
    }
    #pragma unroll
    for (int sl = 0; sl < 4; ++sl) {
        uint4 u = *(const uint4*)(evp + ((size_t)sl * BT + row) * DM + d0);
        const unsigned w[4] = { u.x, u.y, u.z, u.w };
        #pragma unroll
        for (int j = 0; j < 4; ++j) {
            s[2*j]   += bf2f(w[j] & 0xffffu);
            s[2*j+1] += bf2f(w[j] >> 16);
        }
    }
    {
        float4 a = *(const float4*)(b2rw + (size_t)t * DM + d0);
        float4 c = *(const float4*)(b2rw + (size_t)t * DM + d0 + 4);
        s[0]+=a.x; s[1]+=a.y; s[2]+=a.z; s[3]+=a.w; s[4]+=c.x; s[5]+=c.y; s[6]+=c.z; s[7]+=c.w;
    }
    float sum = 0.f, sq = 0.f;
    #pragma unroll
    for (int j = 0; j < 8; ++j) { sum += s[j]; sq += s[j] * s[j]; }
    #pragma unroll
    for (int o = 32; o; o >>= 1) { sum += __shfl_xor(sum, o, 64); sq += __shfl_xor(sq, o, 64); }
    float mean = sum * (1.0f / DM);
    float var  = sq * (1.0f / DM) - mean * mean;
    float rstd = rsqrtf(var + 1e-5f);

    float o8[8];
    #pragma unroll
    for (int j = 0; j < 8; ++j)
        o8[j] = (s[j] - mean) * rstd * g[d0 + j] + b[d0 + j];

    if constexpr (MODE == 0) {
        float4 w0 = make_float4(o8[0], o8[1], o8[2], o8[3]);
        float4 w1 = make_float4(o8[4], o8[5], o8[6], o8[7]);
        *(float4*)(xout + (size_t)row * DM + d0) = w0;
        *(float4*)(xout + (size_t)row * DM + d0 + 4) = w1;
        ushort_t bb[8];
        #pragma unroll
        for (int j = 0; j < 8; ++j) bb[j] = f2bf(o8[j]);
        *(uint4*)(xbf + (size_t)row * DM + d0) = *(const uint4*)bb;
    } else {
        float sum2 = 0.f, sq2 = 0.f;
        #pragma unroll
        for (int j = 0; j < 8; ++j) { sum2 += o8[j]; sq2 += o8[j] * o8[j]; }
        #pragma unroll
        for (int o = 32; o; o >>= 1) { sum2 += __shfl_xor(sum2, o, 64); sq2 += __shfl_xor(sq2, o, 64); }
        float m2 = sum2 * (1.0f / DM);
        float v2 = sq2 * (1.0f / DM) - m2 * m2;
        float r2 = rsqrtf(v2 + 1e-5f);
        ushort_t bb[8];
        #pragma unroll
        for (int j = 0; j < 8; ++j)
            bb[j] = f2bf((o8[j] - m2) * r2 * fg[d0 + j] + fb[d0 + j]);
        *(uint4*)(xbf + (size_t)row * DM + d0) = *(const uint4*)bb;
    }
}

// ---------------------------------------------------------------------------
// 256x256 bf16 GEMM, 16x16x32 MFMA, BK=64, 8 waves. R4-champion 3-phase K-tile:
//   P1: read ALL A frags + B(nh0) | stage B(t+1) -> BAR -> 16 MFMA -> BAR
//   P2: read B(nh1)               | stage A(t+2) -> BAR -> 16 MFMA -> BAR
//   P3: pure 32-MFMA cluster, counted vmcnt(4) (tail: vmcnt(0)), BAR
// Grid mapping: XCD-bijective swizzle -> slice -> 2D groups (nTmG x nTnG,
// tn-fastest inside group). Dead tiles (tn>=nTnTot) return before any barrier.
// C[M,N] = A[M,K] @ Bt[N,K]^T.  AMODE 1: A = xbf[BT][512], K=1536 via row roll.
// EPI 0: Cf[slice]=acc f32.  EPI 1: Cb=bf16(gelu(acc+b1)*rw).  EPI 2: Cb[slice]=bf16(acc).
// ---------------------------------------------------------------------------
template<int EPI, int AMODE>
__global__ __launch_bounds__(512, 2)
void gemm8(const ushort_t* __restrict__ A, const ushort_t* __restrict__ Bt,
           float* __restrict__ Cf, ushort_t* __restrict__ Cb,
           int nTmG, int nTnG, int gridTn, int nPerSlice, int ktiles, int nTnTot,
           int lda, int ldb, int ldc, long long sliceC,
           const float* __restrict__ bias, const float* __restrict__ rwp)
{
    __shared__ ushort_t As[2][256 * 64];
    __shared__ ushort_t Bs[2][256 * 64];

    const int tid  = threadIdx.x;
    const int wave = tid >> 6, lane = tid & 63;
    const int wm = wave >> 2, wn = wave & 3;

    // bijective XCD swizzle (m204)
    int nwg = gridDim.x, bid = blockIdx.x;
    int qq = nwg >> 3, rr = nwg & 7, xc = bid & 7, wi = bid >> 3;
    int wgid = (xc < rr ? xc * (qq + 1) : rr * (qq + 1) + (xc - rr) * qq) + wi;
    int slice = wgid / nPerSlice, rem = wgid - slice * nPerSlice;
    int gsz = nTmG * nTnG;
    int g = rem / gsz, li = rem - g * gsz;
    int gTn = g % gridTn, gTm = g / gridTn;
    int tm = gTm * nTmG + li / nTnG;
    int tn = gTn * nTnG + li % nTnG;
    if (tn >= nTnTot) return;          // uniform early-exit, before any barrier

    const int rowBase = tm * 256, colBase = tn * 256;
    const int kbase = slice * ktiles;
    if (EPI == 0) Cf += (long long)slice * sliceC;
    if (EPI == 2) Cb += (long long)slice * sliceC;

    // staging geometry: lane -> row (lane>>3), phys k-slot (lane&7);
    // source k-slot pre-swizzled so reads XOR by (row&7).
    const int lr  = lane >> 3;
    const int skE = (((lane & 7) ^ (lr & 7)) << 3);
    const ushort_t* Bsrc = Bt + (size_t)(colBase + wave * 32 + lr) * ldb + skE;
    const ushort_t* Asrc = A + (size_t)(rowBase + wave * 32 + lr) * lda + skE;

    auto stageA = [&](int t) {
        ushort_t* d = &As[t & 1][wave * 32 * 64];
        if (AMODE == 0) {
            const ushort_t* s = Asrc + (size_t)(kbase + t) * 64;
            #pragma unroll
            for (int j = 0; j < 4; ++j)
                gload16(s + (size_t)(j * 8) * lda, d + j * 512);
        } else {
            int seg  = t >> 3;                                   // 8 k-tiles per 512-segment
            int dts  = (seg == 0) ? 0 : (seg == 1 ? (T_SEQ - 1) : 1);
            int colE = ((t & 7) << 6) + skE;
            #pragma unroll
            for (int j = 0; j < 4; ++j) {
                int gr = rowBase + wave * 32 + j * 8 + lr;
                int sr = (gr & ~(T_SEQ - 1)) | ((gr + dts) & (T_SEQ - 1));
                gload16(A + (size_t)sr * DM + colE, d + j * 512);
            }
        }
    };
    auto stageB = [&](int t) {
        ushort_t* d = &Bs[t & 1][wave * 32 * 64];
        const ushort_t* s = Bsrc + (size_t)(kbase + t) * 64;
        #pragma unroll
        for (int j = 0; j < 4; ++j)
            gload16(s + (size_t)(j * 8) * ldb, d + j * 512);
    };

    // MFMA fragment read geometry
    const int l15 = lane & 15;
    const int sl0 = (((lane >> 4) ^ (lane & 7))) << 3;       // kstep0 slot offset (elems)
    const int sl1 = (((lane >> 4) + 4) ^ (lane & 7)) << 3;   // kstep1
    const int aoff = (wm * 128 + l15) * 64;
    const int boff = (wn * 64 + l15) * 64;

    f32x4 acc[8][4] = {};
    bf16x8 Ar[2][2][4];     // [mh][kstep][m] — full tile's A frags
    bf16x8 Br[2][2][2];     // [nh][kstep][n]

    auto readAall = [&](int buf) {
        #pragma unroll
        for (int mh = 0; mh < 2; ++mh)
            #pragma unroll
            for (int m = 0; m < 4; ++m) {
                int base = aoff + mh * 4096 + m * 1024;
                Ar[mh][0][m] = *(const bf16x8*)&As[buf][base + sl0];
                Ar[mh][1][m] = *(const bf16x8*)&As[buf][base + sl1];
            }
    };
    auto readB = [&](int buf, int nh) {
        #pragma unroll
        for (int n = 0; n < 2; ++n) {
            int base = boff + nh * 2048 + n * 1024;
            Br[nh][0][n] = *(const bf16x8*)&Bs[buf][base + sl0];
            Br[nh][1][n] = *(const bf16x8*)&Bs[buf][base + sl1];
        }
    };
    auto mmaQ = [&](int mh, int nh) {
        #pragma unroll
        for (int k = 0; k < 2; ++k)
            #pragma unroll
            for (int m = 0; m < 4; ++m)
                #pragma unroll
                for (int n = 0; n < 2; ++n)
                    acc[mh * 4 + m][nh * 2 + n] = __builtin_amdgcn_mfma_f32_16x16x32_bf16(
                        Ar[mh][k][m], Br[nh][k][n], acc[mh * 4 + m][nh * 2 + n], 0, 0, 0);
    };

    // prologue: tile0 (A+B) + tile1's A in flight
    stageA(0); stageB(0);
    if (ktiles > 1) stageA(1);
    VMCNT4();
    BAR();

    for (int t = 0; t < ktiles; ++t) {
        const int cur = t & 1;
        // P1: all A frags + B(nh0); prefetch B(t+1) -> Bs[cur^1]
        readAall(cur); readB(cur, 0);
        if (t + 1 < ktiles) stageB(t + 1);
        BAR();
        __builtin_amdgcn_s_setprio(1); mmaQ(0, 0); __builtin_amdgcn_s_setprio(0);
        BAR();
        // P2: B(nh1); prefetch A(t+2) -> As[cur] (all As[cur] reads retired in P1)
        readB(cur, 1);
        bool pre = (t + 2 < ktiles);
        if (pre) stageA(t + 2);
        BAR();
        __builtin_amdgcn_s_setprio(1); mmaQ(0, 1); __builtin_amdgcn_s_setprio(0);
        BAR();
        // P3: pure MFMA cluster; counted vmcnt
        __builtin_amdgcn_s_setprio(1); mmaQ(1, 1); mmaQ(1, 0); __builtin_amdgcn_s_setprio(0);
        if (pre) { VMCNT4(); } else { VMCNT0(); }
        BAR();
    }

    // epilogue
    const int cl = l15, rl = (lane >> 4) << 2;
    if constexpr (EPI == 0) {
        #pragma unroll
        for (int mf = 0; mf < 8; ++mf) {
            int gr = rowBase + wm * 128 + mf * 16 + rl;
            #pragma unroll
            for (int nf = 0; nf < 4; ++nf) {
                int gc = colBase + wn * 64 + nf * 16 + cl;
                #pragma unroll
                for (int i = 0; i < 4; ++i)
                    Cf[(size_t)(gr + i) * ldc + gc] = acc[mf][nf][i];
            }
        }
    } else if constexpr (EPI == 2) {
        #pragma unroll
        for (int mf = 0; mf < 8; ++mf) {
            int gr = rowBase + wm * 128 + mf * 16 + rl;
            #pragma unroll
            for (int nf = 0; nf < 4; ++nf) {
                int gc = colBase + wn * 64 + nf * 16 + cl;
                #pragma unroll
                for (int i = 0; i < 4; ++i)
                    Cb[(size_t)(gr + i) * ldc + gc] = f2bf(acc[mf][nf][i]);
            }
        }
    } else {
        int r = (colBase + wn * 64) >> 10;   // 64-col span never crosses a rule boundary
        float bv[4];
        #pragma unroll
        for (int nf = 0; nf < 4; ++nf)
            bv[nf] = bias[r * H2 + ((colBase + wn * 64 + nf * 16 + cl) & (H2 - 1))];
        #pragma unroll
        for (int mf = 0; mf < 8; ++mf) {
            int gr = rowBase + wm * 128 + mf * 16 + rl;
            #pragma unroll
            for (int i = 0; i < 4; ++i) {
                float rwv = rwp[((gr + i) & (T_SEQ - 1)) * NR + r];
                #pragma unroll
                for (int nf = 0; nf < 4; ++nf) {
                    int gc = colBase + wn * 64 + nf * 16 + cl;
                    float v = acc[mf][nf][i] + bv[nf];
                    v = gelu_fast(v) * rwv;
                    Cb[(size_t)(gr + i) * ldc + gc] = f2bf(v);
                }
            }
        }
    }
}

extern "C" void kernel_launch(void* const* d_in, const int* in_sizes, int n_in,
                              void* d_out, int out_size, void* d_ws, size_t ws_size,
                              hipStream_t stream)
{
    const int*   tokens = (const int*)d_in[0];
    const float* gate   = (const float*)d_in[1];
    const float* emb    = (const float*)d_in[2];
    const float* pos    = (const float*)d_in[3];
    const float* w1     = (const float*)d_in[4];
    const float* b1     = (const float*)d_in[5];
    const float* w2     = (const float*)d_in[6];
    const float* b2     = (const float*)d_in[7];
    const float* selw   = (const float*)d_in[8];
    const float* selb   = (const float*)d_in[9];
    const float* ng     = (const float*)d_in[10];
    const float* nbm    = (const float*)d_in[11];
    const float* lnfg   = (const float*)d_in[12];
    const float* lnfb   = (const float*)d_in[13];
    const float* headw  = (const float*)d_in[14];
    float* out = (float*)d_out;
    (void)in_sizes; (void)n_in; (void)out_size; (void)ws_size;

    size_t off = 0;
    auto alloc = [&](size_t bytes) {
        void* p = (char*)d_ws + off;
        off += (bytes + 255) & ~(size_t)255;
        return p;
    };
    float*    x    = (float*)alloc((size_t)BT * DM * 4);
    ushort_t* xbf  = (ushort_t*)alloc((size_t)BT * DM * 2);
    ushort_t* evp  = (ushort_t*)alloc((size_t)4 * BT * DM * 2);
    ushort_t* W1t  = (ushort_t*)alloc((size_t)NR * H2 * K1 * 2);
    ushort_t* W2t  = (ushort_t*)alloc((size_t)DM * HN * 2);
    ushort_t* HWt  = (ushort_t*)alloc((size_t)VSZ * DM * 2);
    float*    rw   = (float*)alloc((size_t)T_SEQ * NR * 4);
    float*    b2rw = (float*)alloc((size_t)T_SEQ * DM * 4);
    ushort_t* H    = (ushort_t*)alloc((size_t)BT * HN * 2);

    // --- weight conversion / transpose ---
    transpose_f32_bf16<<<dim3(H2 / 32, K1 / 32, NR), dim3(32, 8), 0, stream>>>(
        w1, W1t, K1, H2, (long long)K1 * H2, (long long)H2 * K1, K1);
    transpose_f32_bf16<<<dim3(DM / 32, H2 / 32, NR), dim3(32, 8), 0, stream>>>(
        w2, W2t, H2, DM, (long long)H2 * DM, (long long)H2, HN);
    transpose_f32_bf16<<<dim3(VSZ / 32, DM / 32, 1), dim3(32, 8), 0, stream>>>(
        headw, HWt, DM, VSZ, 0LL, 0LL, DM);

    // --- x = embed + pos (f32 + bf16); rule weights + b2rw table ---
    embed_pos<<<dim3(BT), dim3(256), 0, stream>>>(tokens, emb, pos, x, xbf);
    rw_kernel<<<dim3(T_SEQ), dim3(64), 0, stream>>>(gate, selw, selb, b2, rw, b2rw);

    // --- 5 CA steps ---
    for (int s = 0; s < NSTEP; ++s) {
        // GEMM1: H = bf16(gelu(NB @ W1 + b1) * rw); groups: tn-shared per XCD (32x1)
        gemm8<1, 1><<<dim3(1024), dim3(512), 0, stream>>>(
            xbf, W1t, nullptr, H, /*nTmG*/32, /*nTnG*/1, /*gridTn*/32,
            /*nPerSlice*/1024, /*ktiles*/K1 / 64, /*nTnTot*/32,
            DM, K1, HN, 0LL, b1, rw);
        // GEMM2: evp[slice] = bf16(H @ W2) (split-K x4); 32x2 group
        gemm8<2, 0><<<dim3(256), dim3(512), 0, stream>>>(
            H, W2t, nullptr, evp, /*nTmG*/32, /*nTnG*/2, /*gridTn*/1,
            /*nPerSlice*/64, /*ktiles*/HN / 64 / 4, /*nTnTot*/2,
            HN, HN, DM, (long long)BT * DM, nullptr, nullptr);
        if (s < NSTEP - 1) {
            ln_kernel<0><<<dim3(BT / 4), dim3(256), 0, stream>>>(
                x, evp, b2rw, ng + s * DM, nbm + s * DM, nullptr, nullptr, x, xbf);
        } else {
            // fused: step-5 LN + final LN -> xbf (x5 never materialized)
            ln_kernel<2><<<dim3(BT / 4), dim3(256), 0, stream>>>(
                x, evp, b2rw, ng + s * DM, nbm + s * DM, lnfg, lnfb, nullptr, xbf);
        }
    }

    // --- head GEMM -> f32 out; 8x4 groups (A 2MB + B 1MB per XCD round, L2-fit) ---
    gemm8<0, 0><<<dim3(4096), dim3(512), 0, stream>>>(
        xbf, HWt, out, nullptr, /*nTmG*/8, /*nTnG*/4, /*gridTn*/32,
        /*nPerSlice*/4096, /*ktiles*/DM / 64, /*nTnTot*/125,
        DM, DM, VSZ, 0LL, nullptr, nullptr);
}